// Round 6
// baseline (911.309 us; speedup 1.0000x reference)
//
#include <hip/hip_runtime.h>
#include <math.h>

typedef _Float16 f16;
typedef _Float16 f16x2 __attribute__((ext_vector_type(2)));
typedef _Float16 f16x4 __attribute__((ext_vector_type(4)));

namespace {
constexpr int B = 4, N = 512, K = 128, C = 256;
constexpr int H8 = 128, W8 = 128, P8 = H8 * W8;
constexpr int H16 = 64, W16 = 64, P16 = H16 * W16;
constexpr int NB = 16;                  // y-bands per batch
constexpr int NBINS = B * NB;           // 64
constexpr int NSAMP = B * K * N;        // 524288 (b,k,n) samples
constexpr int SBLK = 16;                // samples per block (4 waves x 4 groups)
constexpr int NWG_S = NSAMP / SBLK;     // 32768 blocks, %8 == 0
}

__device__ __forceinline__ float fdot2a(f16x2 a, f16x2 b, float c)
{
#if __has_builtin(__builtin_amdgcn_fdot2)
    return __builtin_amdgcn_fdot2(a, b, c, false);
#else
    return c + (float)a.x * (float)b.x + (float)a.y * (float)b.y;
#endif
}

// 16-lane (DPP row) sum reduction, pure VALU pipe
__device__ __forceinline__ float red16_sum(float x)
{
    int t;
    t = __builtin_amdgcn_update_dpp(0, __float_as_int(x), 0xB1,  0xF, 0xF, true);
    x += __int_as_float(t);
    t = __builtin_amdgcn_update_dpp(0, __float_as_int(x), 0x4E,  0xF, 0xF, true);
    x += __int_as_float(t);
    t = __builtin_amdgcn_update_dpp(0, __float_as_int(x), 0x141, 0xF, 0xF, true);
    x += __int_as_float(t);
    t = __builtin_amdgcn_update_dpp(0, __float_as_int(x), 0x140, 0xF, 0xF, true);
    x += __int_as_float(t);
    return x;
}

__device__ __forceinline__ int band_of(float gy)
{
    int band = (int)((gy + 1.0f) * 0.5f * NB);
    return min(NB - 1, max(0, band));
}

// [B,C,P] fp32 -> [B,P,C] fp16 tiled transpose (64x64 tiles, 256 threads)
__global__ __launch_bounds__(256) void k_transpose(
    const float* __restrict__ in, f16* __restrict__ out, int P)
{
    __shared__ float tile[64][65];
    const int b  = blockIdx.z;
    const int p0 = blockIdx.x * 64;
    const int c0 = blockIdx.y * 64;
    const int tid = threadIdx.x;
    const int tp = tid & 63, tq = tid >> 6;
    const float* src = in + (size_t)b * C * P;
    f16* dst = out + (size_t)b * P * C;
#pragma unroll
    for (int i = 0; i < 16; ++i) {
        const int cl = tq + i * 4;
        tile[cl][tp] = src[(size_t)(c0 + cl) * P + (p0 + tp)];
    }
    __syncthreads();
#pragma unroll
    for (int i = 0; i < 16; ++i) {
        const int pl = tq + i * 4;
        dst[(size_t)(p0 + pl) * C + (c0 + tp)] = (f16)tile[tp][pl];
    }
}

// l2-normalize node features -> fp16 [B,N,C]; one wave per node
__global__ __launch_bounds__(256) void k_prenorm(
    const float* __restrict__ nodef, f16* __restrict__ nnf)
{
    const int node = blockIdx.x * 4 + (threadIdx.x >> 6);  // < B*N
    const int lane = threadIdx.x & 63;
    const float4 v = *reinterpret_cast<const float4*>(
        nodef + (size_t)node * C + lane * 4);
    float nn = v.x * v.x + v.y * v.y + v.z * v.z + v.w * v.w;
#pragma unroll
    for (int off = 32; off; off >>= 1) nn += __shfl_xor(nn, off);
    const float inv = __frsqrt_rn(fmaxf(nn, 1e-24f));
    f16x4 o;
    o.x = (f16)(v.x * inv); o.y = (f16)(v.y * inv);
    o.z = (f16)(v.z * inv); o.w = (f16)(v.w * inv);
    *reinterpret_cast<f16x4*>(nnf + (size_t)node * C + lane * 4) = o;
}

// histogram samples into (b, y-band) bins
__global__ __launch_bounds__(256) void k_bin(
    const float* __restrict__ coords, unsigned* __restrict__ hist)
{
    const int sid = blockIdx.x * 256 + threadIdx.x;   // (b*K+k)*N+n linear
    const float gy = coords[(size_t)sid * 2 + 1];
    const int bin = (sid >> 16) * NB + band_of(gy);   // b = sid>>16 (K*N=65536)
    atomicAdd(&hist[bin], 1u);
}

__global__ void k_scan(const unsigned* __restrict__ hist,
                       unsigned* __restrict__ cursor)
{
    if (threadIdx.x == 0) {
        unsigned r = 0;
        for (int i = 0; i < NBINS; ++i) { cursor[i] = r; r += hist[i]; }
    }
}

__global__ __launch_bounds__(256) void k_scatter(
    const float* __restrict__ coords, unsigned* __restrict__ cursor,
    unsigned* __restrict__ order)
{
    const int sid = blockIdx.x * 256 + threadIdx.x;
    const float gy = coords[(size_t)sid * 2 + 1];
    const int bin = (sid >> 16) * NB + band_of(gy);
    const unsigned pos = atomicAdd(&cursor[bin], 1u);
    order[pos] = (unsigned)sid;
}

// bin-ordered sampling; 16-lane group per sample, both scales.
__global__ __launch_bounds__(256) void k_sample(
    const float* __restrict__ nodew,   // [B,N]
    const f16*  __restrict__ nnf,      // [B,N,C] normalized
    const float* __restrict__ rel8,    // [B,P8]
    const float* __restrict__ rel16,   // [B,P16]
    const float* __restrict__ coords,  // [B,K,N,2]
    const f16*  __restrict__ ft8,      // [B,P8,C]
    const f16*  __restrict__ ft16,     // [B,P16,C]
    const unsigned* __restrict__ order,
    float4* __restrict__ sr)           // [B,K,N] {sim0,sim1,rel0,rel1}
{
    // XCD-chunked swizzle: consecutive data chunks stay on one XCD
    const int data = ((blockIdx.x & 7) * (NWG_S / 8)) + (blockIdx.x >> 3);
    const int tid  = threadIdx.x;
    const int gi   = data * SBLK + (tid >> 4);
    const int gl   = tid & 15;
    const int cg   = gl * 16;

    const unsigned sid = order[gi];
    const int n = sid & 511, k = (sid >> 9) & 127, b = sid >> 16;

    const float gx = coords[(size_t)sid * 2 + 0];
    const float gy = coords[(size_t)sid * 2 + 1];
    const float wr = nodew[b * N + n];

    f16x2 nf2[8];
    {
        const f16* np_ = nnf + ((size_t)(b * N + n)) * C + cg;
        float4 r0 = *reinterpret_cast<const float4*>(np_);
        float4 r1 = *reinterpret_cast<const float4*>(np_ + 8);
        const f16x2* h0 = reinterpret_cast<const f16x2*>(&r0);
        const f16x2* h1 = reinterpret_cast<const f16x2*>(&r1);
#pragma unroll
        for (int c = 0; c < 4; ++c) { nf2[c] = h0[c]; nf2[c + 4] = h1[c]; }
    }

    float simv[2], relv[2];
#pragma unroll
    for (int s = 0; s < 2; ++s) {
        const int W_ = s ? W16 : W8;
        const int H_ = s ? H16 : H8;
        const float* __restrict__ relm =
            (s ? rel16 : rel8) + (size_t)b * (s ? P16 : P8);
        const f16* __restrict__ ft =
            (s ? ft16 : ft8) + (size_t)b * (s ? P16 : P8) * C;

        const float ix = ((gx + 1.0f) * W_ - 1.0f) * 0.5f;
        const float iy = ((gy + 1.0f) * H_ - 1.0f) * 0.5f;
        const float x0f = floorf(ix), y0f = floorf(iy);
        const int x0 = (int)x0f, y0 = (int)y0f;
        const int x1 = x0 + 1, y1 = y0 + 1;
        const float fx1 = ix - x0f, fx0 = 1.0f - fx1;
        const float fy1 = iy - y0f, fy0 = 1.0f - fy1;
        const bool vx0 = (x0 >= 0) && (x0 < W_);
        const bool vx1 = (x1 >= 0) && (x1 < W_);
        const bool vy0 = (y0 >= 0) && (y0 < H_);
        const bool vy1 = (y1 >= 0) && (y1 < H_);
        float w[4];
        w[0] = (vx0 && vy0) ? fx0 * fy0 : 0.0f;
        w[1] = (vx1 && vy0) ? fx1 * fy0 : 0.0f;
        w[2] = (vx0 && vy1) ? fx0 * fy1 : 0.0f;
        w[3] = (vx1 && vy1) ? fx1 * fy1 : 0.0f;
        const int cx0 = min(max(x0, 0), W_ - 1);
        const int cx1 = min(max(x1, 0), W_ - 1);
        const int cy0 = min(max(y0, 0), H_ - 1);
        const int cy1 = min(max(y1, 0), H_ - 1);
        int p[4];
        p[0] = cy0 * W_ + cx0; p[1] = cy0 * W_ + cx1;
        p[2] = cy1 * W_ + cx0; p[3] = cy1 * W_ + cx1;

        float4 ra[4], rb[4];
#pragma unroll
        for (int t = 0; t < 4; ++t) {
            const f16* tp = ft + (size_t)p[t] * C + cg;
            ra[t] = *reinterpret_cast<const float4*>(tp);
            rb[t] = *reinterpret_cast<const float4*>(tp + 8);
        }

        f16x2 v[8];
        {
            const f16 h = (f16)w[0];
            const f16x2 w2 = {h, h};
            const f16x2* a0 = reinterpret_cast<const f16x2*>(&ra[0]);
            const f16x2* b0 = reinterpret_cast<const f16x2*>(&rb[0]);
#pragma unroll
            for (int c = 0; c < 4; ++c) {
                v[c]     = w2 * a0[c];
                v[c + 4] = w2 * b0[c];
            }
        }
#pragma unroll
        for (int t = 1; t < 4; ++t) {
            const f16 h = (f16)w[t];
            const f16x2 w2 = {h, h};
            const f16x2* at = reinterpret_cast<const f16x2*>(&ra[t]);
            const f16x2* bt = reinterpret_cast<const f16x2*>(&rb[t]);
#pragma unroll
            for (int c = 0; c < 4; ++c) {
                v[c]     += w2 * at[c];
                v[c + 4] += w2 * bt[c];
            }
        }

        float dot = 0.0f, n2 = 0.0f;
#pragma unroll
        for (int c = 0; c < 8; ++c) {
            dot = fdot2a(nf2[c], v[c], dot);
            n2  = fdot2a(v[c], v[c], n2);
        }
        dot = red16_sum(dot);
        n2  = red16_sum(n2);

        simv[s] = dot * __frsqrt_rn(fmaxf(n2, 1e-24f));
        relv[s] = w[0] * relm[p[0]] + w[1] * relm[p[1]]
                + w[2] * relm[p[2]] + w[3] * relm[p[3]];
    }

    if (gl == 0) {
        sr[(size_t)(b * K + k) * N + n] =
            make_float4(simv[0], simv[1], wr + relv[0], wr + relv[1]);
    }
}

// per (b,k): softmax over N*S of rel, weighted sum of sim
__global__ __launch_bounds__(256) void k_logits(
    const float4* __restrict__ sr, const float* __restrict__ lscale,
    float* __restrict__ logits)
{
    const int bk = blockIdx.x;
    const int tid = threadIdx.x;
    const int lane = tid & 63, wid = tid >> 6;
    const float4* sp = sr + (size_t)bk * N;
    __shared__ float red0[4], red1[4], red2[4];

    float4 e0 = sp[tid], e1 = sp[tid + 256];
    float m = fmaxf(fmaxf(e0.z, e0.w), fmaxf(e1.z, e1.w));
#pragma unroll
    for (int off = 32; off; off >>= 1) m = fmaxf(m, __shfl_xor(m, off));
    if (lane == 0) red0[wid] = m;
    __syncthreads();
    m = fmaxf(fmaxf(red0[0], red0[1]), fmaxf(red0[2], red0[3]));

    const float a0 = expf(e0.z - m), a1 = expf(e0.w - m);
    const float b0 = expf(e1.z - m), b1 = expf(e1.w - m);
    float se = a0 + a1 + b0 + b1;
    float ss = a0 * e0.x + a1 * e0.y + b0 * e1.x + b1 * e1.y;
#pragma unroll
    for (int off = 32; off; off >>= 1) {
        se += __shfl_xor(se, off);
        ss += __shfl_xor(ss, off);
    }
    if (lane == 0) { red1[wid] = se; red2[wid] = ss; }
    __syncthreads();
    if (tid == 0) {
        const float tse = red1[0] + red1[1] + red1[2] + red1[3];
        const float tss = red2[0] + red2[1] + red2[2] + red2[3];
        logits[bk] = (tss / tse) * expf(lscale[0]);
    }
}

// final softmax over K per b
__global__ __launch_bounds__(64) void k_out(
    const float* __restrict__ logits, float* __restrict__ out)
{
    const int b = blockIdx.x;
    const int lane = threadIdx.x;
    const float v0 = logits[b * K + lane];
    const float v1 = logits[b * K + lane + 64];
    float m = fmaxf(v0, v1);
#pragma unroll
    for (int off = 32; off; off >>= 1) m = fmaxf(m, __shfl_xor(m, off));
    const float e0 = expf(v0 - m), e1 = expf(v1 - m);
    float se = e0 + e1;
#pragma unroll
    for (int off = 32; off; off >>= 1) se += __shfl_xor(se, off);
    out[b * K + lane] = e0 / se;
    out[b * K + lane + 64] = e1 / se;
}

extern "C" void kernel_launch(void* const* d_in, const int* in_sizes, int n_in,
                              void* d_out, int out_size, void* d_ws, size_t ws_size,
                              hipStream_t stream)
{
    const float* nodew  = (const float*)d_in[0];
    const float* nodef  = (const float*)d_in[1];
    const float* rel8   = (const float*)d_in[2];
    const float* feat8  = (const float*)d_in[3];
    const float* rel16  = (const float*)d_in[4];
    const float* feat16 = (const float*)d_in[5];
    const float* coords = (const float*)d_in[6];
    const float* lscale = (const float*)d_in[7];

    char* ws = (char*)d_ws;
    size_t off = 0;
    f16* ft8  = (f16*)(ws + off); off += (size_t)B * P8 * C * 2;     // 33.5 MB
    f16* ft16 = (f16*)(ws + off); off += (size_t)B * P16 * C * 2;    //  8.4 MB
    f16* nnf  = (f16*)(ws + off); off += (size_t)B * N * C * 2;      //  1.0 MB
    float4* sr = (float4*)(ws + off); off += (size_t)NSAMP / 1 * 0 + (size_t)(B * K * N) * 16; // 4.2 MB
    float* logits = (float*)(ws + off); off += (size_t)B * K * 4;
    unsigned* order  = (unsigned*)(ws + off); off += (size_t)NSAMP * 4; // 2.1 MB
    unsigned* hist   = (unsigned*)(ws + off); off += NBINS * 4;
    unsigned* cursor = (unsigned*)(ws + off); off += NBINS * 4;
    float* out = (float*)d_out;

    hipMemsetAsync(hist, 0, NBINS * sizeof(unsigned), stream);

    hipLaunchKernelGGL(k_transpose, dim3(P8 / 64, C / 64, B), dim3(256), 0, stream,
                       feat8, ft8, P8);
    hipLaunchKernelGGL(k_transpose, dim3(P16 / 64, C / 64, B), dim3(256), 0, stream,
                       feat16, ft16, P16);
    hipLaunchKernelGGL(k_prenorm, dim3(B * N / 4), dim3(256), 0, stream,
                       nodef, nnf);
    hipLaunchKernelGGL(k_bin, dim3(NSAMP / 256), dim3(256), 0, stream,
                       coords, hist);
    hipLaunchKernelGGL(k_scan, dim3(1), dim3(64), 0, stream, hist, cursor);
    hipLaunchKernelGGL(k_scatter, dim3(NSAMP / 256), dim3(256), 0, stream,
                       coords, cursor, order);
    hipLaunchKernelGGL(k_sample, dim3(NWG_S), dim3(256), 0, stream,
                       nodew, nnf, rel8, rel16, coords, ft8, ft16, order, sr);
    hipLaunchKernelGGL(k_logits, dim3(B * K), dim3(256), 0, stream,
                       sr, lscale, logits);
    hipLaunchKernelGGL(k_out, dim3(B), dim3(64), 0, stream, logits, out);
}

// Round 7
// 105.042 us; speedup vs baseline: 8.6756x; 8.6756x over previous
//
#include <hip/hip_runtime.h>
#include <math.h>

typedef _Float16 f16;
typedef _Float16 f16x2 __attribute__((ext_vector_type(2)));
typedef _Float16 f16x4 __attribute__((ext_vector_type(4)));

namespace {
constexpr int B = 4, N = 512, K = 128, C = 256;
constexpr int H8 = 128, W8 = 128, P8 = H8 * W8;
constexpr int H16 = 64, W16 = 64, P16 = H16 * W16;
constexpr int NB = 16;                  // y-bands per batch
constexpr int NBINS = B * NB;           // 64
constexpr int NSAMP = B * K * N;        // 524288
constexpr int CAP = 4608;               // slots per bin: mean 4096 + 8 sigma
constexpr int SLOTS = NBINS * CAP;      // 294912
constexpr int NWGS = SLOTS / 32;        // 9216 blocks, 32 samples each (%8==0)
}

__device__ __forceinline__ float fdot2a(f16x2 a, f16x2 b, float c)
{
#if __has_builtin(__builtin_amdgcn_fdot2)
    return __builtin_amdgcn_fdot2(a, b, c, false);
#else
    return c + (float)a.x * (float)b.x + (float)a.y * (float)b.y;
#endif
}

// 16-lane (DPP row) sum reduction, pure VALU pipe
__device__ __forceinline__ float red16_sum(float x)
{
    int t;
    t = __builtin_amdgcn_update_dpp(0, __float_as_int(x), 0xB1,  0xF, 0xF, true);
    x += __int_as_float(t);
    t = __builtin_amdgcn_update_dpp(0, __float_as_int(x), 0x4E,  0xF, 0xF, true);
    x += __int_as_float(t);
    t = __builtin_amdgcn_update_dpp(0, __float_as_int(x), 0x141, 0xF, 0xF, true);
    x += __int_as_float(t);
    t = __builtin_amdgcn_update_dpp(0, __float_as_int(x), 0x140, 0xF, 0xF, true);
    x += __int_as_float(t);
    return x;
}

__device__ __forceinline__ int band_of(float gy)
{
    int band = (int)((gy + 1.0f) * 0.5f * NB);
    return min(NB - 1, max(0, band));
}

// [B,C,P] fp32 -> [B,P,C] fp16 tiled transpose (64x64 tiles, 256 threads)
__global__ __launch_bounds__(256) void k_transpose(
    const float* __restrict__ in, f16* __restrict__ out, int P)
{
    __shared__ float tile[64][65];
    const int b  = blockIdx.z;
    const int p0 = blockIdx.x * 64;
    const int c0 = blockIdx.y * 64;
    const int tid = threadIdx.x;
    const int tp = tid & 63, tq = tid >> 6;
    const float* src = in + (size_t)b * C * P;
    f16* dst = out + (size_t)b * P * C;
#pragma unroll
    for (int i = 0; i < 16; ++i) {
        const int cl = tq + i * 4;
        tile[cl][tp] = src[(size_t)(c0 + cl) * P + (p0 + tp)];
    }
    __syncthreads();
#pragma unroll
    for (int i = 0; i < 16; ++i) {
        const int pl = tq + i * 4;
        dst[(size_t)(p0 + pl) * C + (c0 + tp)] = (f16)tile[tp][pl];
    }
}

// l2-normalize node features -> fp16 [B,N,C]; one wave per node
__global__ __launch_bounds__(256) void k_prenorm(
    const float* __restrict__ nodef, f16* __restrict__ nnf)
{
    const int node = blockIdx.x * 4 + (threadIdx.x >> 6);
    const int lane = threadIdx.x & 63;
    const float4 v = *reinterpret_cast<const float4*>(
        nodef + (size_t)node * C + lane * 4);
    float nn = v.x * v.x + v.y * v.y + v.z * v.z + v.w * v.w;
#pragma unroll
    for (int off = 32; off; off >>= 1) nn += __shfl_xor(nn, off);
    const float inv = __frsqrt_rn(fmaxf(nn, 1e-24f));
    f16x4 o;
    o.x = (f16)(v.x * inv); o.y = (f16)(v.y * inv);
    o.z = (f16)(v.z * inv); o.w = (f16)(v.w * inv);
    *reinterpret_cast<f16x4*>(nnf + (size_t)node * C + lane * 4) = o;
}

// LDS-aggregated binning scatter: 512 samples/block, fixed-capacity bins.
// Global atomics: one range-reserve per (block, active bin) only.
__global__ __launch_bounds__(256) void k_scatter(
    const float* __restrict__ coords, unsigned* __restrict__ cursor,
    unsigned* __restrict__ order)
{
    __shared__ unsigned cnt[NBINS], base[NBINS];
    const int tid = threadIdx.x;
    const int sid0 = blockIdx.x * 512;

    if (tid < NBINS) cnt[tid] = 0;
    __syncthreads();

    int bin[2];
#pragma unroll
    for (int j = 0; j < 2; ++j) {
        const int sid = sid0 + j * 256 + tid;
        const float gy = coords[(size_t)sid * 2 + 1];
        bin[j] = (sid >> 16) * NB + band_of(gy);
        atomicAdd(&cnt[bin[j]], 1u);
    }
    __syncthreads();
    if (tid < NBINS) {
        base[tid] = cnt[tid] ? atomicAdd(&cursor[tid], cnt[tid]) : 0u;
    }
    __syncthreads();
    if (tid < NBINS) cnt[tid] = 0;
    __syncthreads();
#pragma unroll
    for (int j = 0; j < 2; ++j) {
        const int sid = sid0 + j * 256 + tid;
        const unsigned rank = atomicAdd(&cnt[bin[j]], 1u);
        const unsigned r = base[bin[j]] + rank;
        if (r < CAP) order[(size_t)bin[j] * CAP + r] = (unsigned)sid;
    }
}

// bin-ordered sampling; 16-lane group per 2 samples, 4-phase depth-2 pipeline.
__global__ __launch_bounds__(256) void k_sample(
    const float* __restrict__ nodew,   // [B,N]
    const f16*  __restrict__ nnf,      // [B,N,C] normalized fp16
    const float* __restrict__ rel8,    // [B,P8]
    const float* __restrict__ rel16,   // [B,P16]
    const float* __restrict__ coords,  // [B,K,N,2]
    const f16*  __restrict__ ft8,      // [B,P8,C]
    const f16*  __restrict__ ft16,     // [B,P16,C]
    const unsigned* __restrict__ order,
    float4* __restrict__ sr)           // [B,K,N] {sim0,sim1,rel0,rel1}
{
    // XCD-chunked swizzle: each XCD walks a contiguous slice of bin space
    const int data = ((blockIdx.x & 7) * (NWGS / 8)) + (blockIdx.x >> 3);
    const int tid = threadIdx.x;
    const int grp = tid >> 4, gl = tid & 15, cg = gl * 16;
    const int slot0 = data * 32 + grp * 2;

    unsigned sid[2];
    sid[0] = order[slot0];
    sid[1] = order[slot0 + 1];

    bool val[2];
    int bb[2], kv[2], nv[2];
    float gx[2], gy[2], wr[2];
    f16x2 nf2[2][8];
#pragma unroll
    for (int j = 0; j < 2; ++j) {
        val[j] = (sid[j] != 0xFFFFFFFFu);
        const unsigned s = val[j] ? sid[j] : 0u;
        nv[j] = s & 511; kv[j] = (s >> 9) & 127; bb[j] = (int)(s >> 16);
        gx[j] = coords[(size_t)s * 2 + 0];
        gy[j] = coords[(size_t)s * 2 + 1];
        wr[j] = nodew[bb[j] * N + nv[j]];
        const f16* np_ = nnf + ((size_t)(bb[j] * N + nv[j])) * C + cg;
        float4 r0 = *reinterpret_cast<const float4*>(np_);
        float4 r1 = *reinterpret_cast<const float4*>(np_ + 8);
        const f16x2* h0 = reinterpret_cast<const f16x2*>(&r0);
        const f16x2* h1 = reinterpret_cast<const f16x2*>(&r1);
#pragma unroll
        for (int c = 0; c < 4; ++c) { nf2[j][c] = h0[c]; nf2[j][c + 4] = h1[c]; }
    }

    // precompute 4 phases (j=sample, s=scale): taps, weights, rel blends
    int   pp[4][4];
    f16x2 ww[4][4];
    float srv[4];
    const f16* fb[4];
#pragma unroll
    for (int ph = 0; ph < 4; ++ph) {
        const int j = ph >> 1, s = ph & 1;
        const int W_ = s ? W16 : W8;
        const int H_ = s ? H16 : H8;
        const float* __restrict__ relm =
            (s ? rel16 : rel8) + (size_t)bb[j] * (s ? P16 : P8);
        fb[ph] = (s ? ft16 : ft8) + (size_t)bb[j] * (s ? P16 : P8) * C;

        const float ix = ((gx[j] + 1.0f) * W_ - 1.0f) * 0.5f;
        const float iy = ((gy[j] + 1.0f) * H_ - 1.0f) * 0.5f;
        const float x0f = floorf(ix), y0f = floorf(iy);
        const int x0 = (int)x0f, y0 = (int)y0f;
        const int x1 = x0 + 1, y1 = y0 + 1;
        const float fx1 = ix - x0f, fx0 = 1.0f - fx1;
        const float fy1 = iy - y0f, fy0 = 1.0f - fy1;
        const bool vx0 = (x0 >= 0) && (x0 < W_);
        const bool vx1 = (x1 >= 0) && (x1 < W_);
        const bool vy0 = (y0 >= 0) && (y0 < H_);
        const bool vy1 = (y1 >= 0) && (y1 < H_);
        float w[4];
        w[0] = (vx0 && vy0) ? fx0 * fy0 : 0.0f;
        w[1] = (vx1 && vy0) ? fx1 * fy0 : 0.0f;
        w[2] = (vx0 && vy1) ? fx0 * fy1 : 0.0f;
        w[3] = (vx1 && vy1) ? fx1 * fy1 : 0.0f;
        const int cx0 = min(max(x0, 0), W_ - 1);
        const int cx1 = min(max(x1, 0), W_ - 1);
        const int cy0 = min(max(y0, 0), H_ - 1);
        const int cy1 = min(max(y1, 0), H_ - 1);
        pp[ph][0] = cy0 * W_ + cx0; pp[ph][1] = cy0 * W_ + cx1;
        pp[ph][2] = cy1 * W_ + cx0; pp[ph][3] = cy1 * W_ + cx1;
        srv[ph] = w[0] * relm[pp[ph][0]] + w[1] * relm[pp[ph][1]]
                + w[2] * relm[pp[ph][2]] + w[3] * relm[pp[ph][3]];
#pragma unroll
        for (int t = 0; t < 4; ++t) {
            const f16 h = (f16)w[t];
            ww[ph][t] = f16x2{h, h};
        }
    }

    // depth-2 pipelined: load phase ph+1 while computing ph
    float4 ra[2][4], rb[2][4];
#pragma unroll
    for (int t = 0; t < 4; ++t) {
        const f16* tp = fb[0] + (size_t)pp[0][t] * C + cg;
        ra[0][t] = *reinterpret_cast<const float4*>(tp);
        rb[0][t] = *reinterpret_cast<const float4*>(tp + 8);
    }

    float simv[4];
#pragma unroll
    for (int ph = 0; ph < 4; ++ph) {
        const int cur = ph & 1, nxt = cur ^ 1;
        if (ph < 3) {
#pragma unroll
            for (int t = 0; t < 4; ++t) {
                const f16* tp = fb[ph + 1] + (size_t)pp[ph + 1][t] * C + cg;
                ra[nxt][t] = *reinterpret_cast<const float4*>(tp);
                rb[nxt][t] = *reinterpret_cast<const float4*>(tp + 8);
            }
        }

        f16x2 v[8];
        {
            const f16x2* a0 = reinterpret_cast<const f16x2*>(&ra[cur][0]);
            const f16x2* b0 = reinterpret_cast<const f16x2*>(&rb[cur][0]);
#pragma unroll
            for (int c = 0; c < 4; ++c) {
                v[c]     = ww[ph][0] * a0[c];
                v[c + 4] = ww[ph][0] * b0[c];
            }
        }
#pragma unroll
        for (int t = 1; t < 4; ++t) {
            const f16x2* at = reinterpret_cast<const f16x2*>(&ra[cur][t]);
            const f16x2* bt = reinterpret_cast<const f16x2*>(&rb[cur][t]);
#pragma unroll
            for (int c = 0; c < 4; ++c) {
                v[c]     += ww[ph][t] * at[c];
                v[c + 4] += ww[ph][t] * bt[c];
            }
        }

        float dot = 0.0f, n2 = 0.0f;
        const int j = ph >> 1;
#pragma unroll
        for (int c = 0; c < 8; ++c) {
            dot = fdot2a(nf2[j][c], v[c], dot);
            n2  = fdot2a(v[c], v[c], n2);
        }
        dot = red16_sum(dot);
        n2  = red16_sum(n2);
        simv[ph] = dot * __frsqrt_rn(fmaxf(n2, 1e-24f));
    }

#pragma unroll
    for (int j = 0; j < 2; ++j) {
        if (val[j] && gl == 0) {
            sr[(size_t)(bb[j] * K + kv[j]) * N + nv[j]] =
                make_float4(simv[j * 2], simv[j * 2 + 1],
                            wr[j] + srv[j * 2], wr[j] + srv[j * 2 + 1]);
        }
    }
}

// per (b,k): softmax over N*S of rel, weighted sum of sim
__global__ __launch_bounds__(256) void k_logits(
    const float4* __restrict__ sr, const float* __restrict__ lscale,
    float* __restrict__ logits)
{
    const int bk = blockIdx.x;
    const int tid = threadIdx.x;
    const int lane = tid & 63, wid = tid >> 6;
    const float4* sp = sr + (size_t)bk * N;
    __shared__ float red0[4], red1[4], red2[4];

    float4 e0 = sp[tid], e1 = sp[tid + 256];
    float m = fmaxf(fmaxf(e0.z, e0.w), fmaxf(e1.z, e1.w));
#pragma unroll
    for (int off = 32; off; off >>= 1) m = fmaxf(m, __shfl_xor(m, off));
    if (lane == 0) red0[wid] = m;
    __syncthreads();
    m = fmaxf(fmaxf(red0[0], red0[1]), fmaxf(red0[2], red0[3]));

    const float a0 = expf(e0.z - m), a1 = expf(e0.w - m);
    const float b0 = expf(e1.z - m), b1 = expf(e1.w - m);
    float se = a0 + a1 + b0 + b1;
    float ss = a0 * e0.x + a1 * e0.y + b0 * e1.x + b1 * e1.y;
#pragma unroll
    for (int off = 32; off; off >>= 1) {
        se += __shfl_xor(se, off);
        ss += __shfl_xor(ss, off);
    }
    if (lane == 0) { red1[wid] = se; red2[wid] = ss; }
    __syncthreads();
    if (tid == 0) {
        const float tse = red1[0] + red1[1] + red1[2] + red1[3];
        const float tss = red2[0] + red2[1] + red2[2] + red2[3];
        logits[bk] = (tss / tse) * expf(lscale[0]);
    }
}

// final softmax over K per b
__global__ __launch_bounds__(64) void k_out(
    const float* __restrict__ logits, float* __restrict__ out)
{
    const int b = blockIdx.x;
    const int lane = threadIdx.x;
    const float v0 = logits[b * K + lane];
    const float v1 = logits[b * K + lane + 64];
    float m = fmaxf(v0, v1);
#pragma unroll
    for (int off = 32; off; off >>= 1) m = fmaxf(m, __shfl_xor(m, off));
    const float e0 = expf(v0 - m), e1 = expf(v1 - m);
    float se = e0 + e1;
#pragma unroll
    for (int off = 32; off; off >>= 1) se += __shfl_xor(se, off);
    out[b * K + lane] = e0 / se;
    out[b * K + lane + 64] = e1 / se;
}

extern "C" void kernel_launch(void* const* d_in, const int* in_sizes, int n_in,
                              void* d_out, int out_size, void* d_ws, size_t ws_size,
                              hipStream_t stream)
{
    const float* nodew  = (const float*)d_in[0];
    const float* nodef  = (const float*)d_in[1];
    const float* rel8   = (const float*)d_in[2];
    const float* feat8  = (const float*)d_in[3];
    const float* rel16  = (const float*)d_in[4];
    const float* feat16 = (const float*)d_in[5];
    const float* coords = (const float*)d_in[6];
    const float* lscale = (const float*)d_in[7];

    char* ws = (char*)d_ws;
    size_t off = 0;
    f16* ft8  = (f16*)(ws + off); off += (size_t)B * P8 * C * 2;     // 33.5 MB
    f16* ft16 = (f16*)(ws + off); off += (size_t)B * P16 * C * 2;    //  8.4 MB
    f16* nnf  = (f16*)(ws + off); off += (size_t)B * N * C * 2;      //  1.0 MB
    float4* sr = (float4*)(ws + off); off += (size_t)NSAMP * 16;     //  8.4 MB
    float* logits = (float*)(ws + off); off += (size_t)B * K * 4;
    unsigned* order  = (unsigned*)(ws + off); off += (size_t)SLOTS * 4; // 1.2 MB
    unsigned* cursor = (unsigned*)(ws + off); off += NBINS * 4;
    float* out = (float*)d_out;

    hipMemsetAsync(order, 0xFF, (size_t)SLOTS * sizeof(unsigned), stream);
    hipMemsetAsync(cursor, 0, NBINS * sizeof(unsigned), stream);

    hipLaunchKernelGGL(k_transpose, dim3(P8 / 64, C / 64, B), dim3(256), 0, stream,
                       feat8, ft8, P8);
    hipLaunchKernelGGL(k_transpose, dim3(P16 / 64, C / 64, B), dim3(256), 0, stream,
                       feat16, ft16, P16);
    hipLaunchKernelGGL(k_prenorm, dim3(B * N / 4), dim3(256), 0, stream,
                       nodef, nnf);
    hipLaunchKernelGGL(k_scatter, dim3(NSAMP / 512), dim3(256), 0, stream,
                       coords, cursor, order);
    hipLaunchKernelGGL(k_sample, dim3(NWGS), dim3(256), 0, stream,
                       nodew, nnf, rel8, rel16, coords, ft8, ft16, order, sr);
    hipLaunchKernelGGL(k_logits, dim3(B * K), dim3(256), 0, stream,
                       sr, lscale, logits);
    hipLaunchKernelGGL(k_out, dim3(B), dim3(64), 0, stream, logits, out);
}

// Round 8
// 103.439 us; speedup vs baseline: 8.8101x; 1.0155x over previous
//
#include <hip/hip_runtime.h>
#include <math.h>

typedef _Float16 f16;
typedef _Float16 f16x2 __attribute__((ext_vector_type(2)));
typedef _Float16 f16x4 __attribute__((ext_vector_type(4)));

namespace {
constexpr int B = 4, N = 512, K = 128, C = 256;
constexpr int H8 = 128, W8 = 128, P8 = H8 * W8;
constexpr int H16 = 64, W16 = 64, P16 = H16 * W16;
constexpr int NBG = 32;                 // 32x32 normalized tile grid
constexpr int LBINS = NBG * NBG;        // 1024 bins per batch
constexpr int NBINS = B * LBINS;        // 4096
constexpr int NSAMP = B * K * N;        // 524288
constexpr int NWGS = NSAMP / 32;        // 16384 blocks, 32 samples each
}

__device__ __forceinline__ float fdot2a(f16x2 a, f16x2 b, float c)
{
#if __has_builtin(__builtin_amdgcn_fdot2)
    return __builtin_amdgcn_fdot2(a, b, c, false);
#else
    return c + (float)a.x * (float)b.x + (float)a.y * (float)b.y;
#endif
}

// 16-lane (DPP row) sum reduction, pure VALU pipe
__device__ __forceinline__ float red16_sum(float x)
{
    int t;
    t = __builtin_amdgcn_update_dpp(0, __float_as_int(x), 0xB1,  0xF, 0xF, true);
    x += __int_as_float(t);
    t = __builtin_amdgcn_update_dpp(0, __float_as_int(x), 0x4E,  0xF, 0xF, true);
    x += __int_as_float(t);
    t = __builtin_amdgcn_update_dpp(0, __float_as_int(x), 0x141, 0xF, 0xF, true);
    x += __int_as_float(t);
    t = __builtin_amdgcn_update_dpp(0, __float_as_int(x), 0x140, 0xF, 0xF, true);
    x += __int_as_float(t);
    return x;
}

__device__ __forceinline__ int band32(float g)
{
    int v = (int)((g + 1.0f) * 0.5f * NBG);
    return min(NBG - 1, max(0, v));
}

// [B,C,P] fp32 -> [B,P,C] fp16 tiled transpose (64x64 tiles, 256 threads)
__global__ __launch_bounds__(256) void k_transpose(
    const float* __restrict__ in, f16* __restrict__ out, int P)
{
    __shared__ float tile[64][65];
    const int b  = blockIdx.z;
    const int p0 = blockIdx.x * 64;
    const int c0 = blockIdx.y * 64;
    const int tid = threadIdx.x;
    const int tp = tid & 63, tq = tid >> 6;
    const float* src = in + (size_t)b * C * P;
    f16* dst = out + (size_t)b * P * C;
#pragma unroll
    for (int i = 0; i < 16; ++i) {
        const int cl = tq + i * 4;
        tile[cl][tp] = src[(size_t)(c0 + cl) * P + (p0 + tp)];
    }
    __syncthreads();
#pragma unroll
    for (int i = 0; i < 16; ++i) {
        const int pl = tq + i * 4;
        dst[(size_t)(p0 + pl) * C + (c0 + tp)] = (f16)tile[tp][pl];
    }
}

// l2-normalize node features -> fp16 [B,N,C]; one wave per node
__global__ __launch_bounds__(256) void k_prenorm(
    const float* __restrict__ nodef, f16* __restrict__ nnf)
{
    const int node = blockIdx.x * 4 + (threadIdx.x >> 6);
    const int lane = threadIdx.x & 63;
    const float4 v = *reinterpret_cast<const float4*>(
        nodef + (size_t)node * C + lane * 4);
    float nn = v.x * v.x + v.y * v.y + v.z * v.z + v.w * v.w;
#pragma unroll
    for (int off = 32; off; off >>= 1) nn += __shfl_xor(nn, off);
    const float inv = __frsqrt_rn(fmaxf(nn, 1e-24f));
    f16x4 o;
    o.x = (f16)(v.x * inv); o.y = (f16)(v.y * inv);
    o.z = (f16)(v.z * inv); o.w = (f16)(v.w * inv);
    *reinterpret_cast<f16x4*>(nnf + (size_t)node * C + lane * 4) = o;
}

// pass 1: LDS-aggregated bin counts (512 consecutive sids/block -> one b)
__global__ __launch_bounds__(256) void k_count(
    const float* __restrict__ coords, unsigned* __restrict__ hist)
{
    __shared__ unsigned cnt[LBINS];
    const int tid = threadIdx.x;
    const int sid0 = blockIdx.x * 512;
    const int b = sid0 >> 16;
    for (int i = tid; i < LBINS; i += 256) cnt[i] = 0;
    __syncthreads();
#pragma unroll
    for (int j = 0; j < 2; ++j) {
        const int sid = sid0 + j * 256 + tid;
        const float gx = coords[(size_t)sid * 2 + 0];
        const float gy = coords[(size_t)sid * 2 + 1];
        atomicAdd(&cnt[band32(gy) * NBG + band32(gx)], 1u);
    }
    __syncthreads();
    for (int i = tid; i < LBINS; i += 256)
        if (cnt[i]) atomicAdd(&hist[b * LBINS + i], cnt[i]);
}

// pass 2: exclusive scan of 4096 bin counts (one block, 256 thr x 16 elems)
__global__ __launch_bounds__(256) void k_scan(
    const unsigned* __restrict__ hist, unsigned* __restrict__ cursor)
{
    __shared__ unsigned sums[256];
    const int t = threadIdx.x;
    unsigned v[16];
    unsigned s = 0;
#pragma unroll
    for (int i = 0; i < 16; ++i) { v[i] = s; s += hist[t * 16 + i]; }
    sums[t] = s;
    __syncthreads();
    for (int off = 1; off < 256; off <<= 1) {
        const unsigned x = (t >= off) ? sums[t - off] : 0u;
        __syncthreads();
        sums[t] += x;
        __syncthreads();
    }
    const unsigned pre = (t == 0) ? 0u : sums[t - 1];
#pragma unroll
    for (int i = 0; i < 16; ++i) cursor[t * 16 + i] = pre + v[i];
}

// pass 3: LDS-aggregated dense scatter (range-reserve per active bin)
__global__ __launch_bounds__(256) void k_scatter(
    const float* __restrict__ coords, unsigned* __restrict__ cursor,
    unsigned* __restrict__ order)
{
    __shared__ unsigned cnt[LBINS], base[LBINS];
    const int tid = threadIdx.x;
    const int sid0 = blockIdx.x * 512;
    const int b = sid0 >> 16;
    for (int i = tid; i < LBINS; i += 256) cnt[i] = 0;
    __syncthreads();
    int bl[2];
#pragma unroll
    for (int j = 0; j < 2; ++j) {
        const int sid = sid0 + j * 256 + tid;
        const float gx = coords[(size_t)sid * 2 + 0];
        const float gy = coords[(size_t)sid * 2 + 1];
        bl[j] = band32(gy) * NBG + band32(gx);
        atomicAdd(&cnt[bl[j]], 1u);
    }
    __syncthreads();
    for (int i = tid; i < LBINS; i += 256)
        base[i] = cnt[i] ? atomicAdd(&cursor[b * LBINS + i], cnt[i]) : 0u;
    __syncthreads();
    for (int i = tid; i < LBINS; i += 256) cnt[i] = 0;
    __syncthreads();
#pragma unroll
    for (int j = 0; j < 2; ++j) {
        const int sid = sid0 + j * 256 + tid;
        const unsigned r = base[bl[j]] + atomicAdd(&cnt[bl[j]], 1u);
        order[r] = (unsigned)sid;
    }
}

// bin-ordered sampling; 16-lane group per 2 samples, 4-phase depth-2 pipeline.
// phase order j0s0, j1s0, j0s1, j1s1 keeps each scale's L1 tile hot.
__global__ __launch_bounds__(256) void k_sample(
    const float* __restrict__ nodew,   // [B,N]
    const f16*  __restrict__ nnf,      // [B,N,C] normalized fp16
    const float* __restrict__ rel8,    // [B,P8]
    const float* __restrict__ rel16,   // [B,P16]
    const float* __restrict__ coords,  // [B,K,N,2]
    const f16*  __restrict__ ft8,      // [B,P8,C]
    const f16*  __restrict__ ft16,     // [B,P16,C]
    const unsigned* __restrict__ order,
    float4* __restrict__ sr)           // [B,K,N] {sim0,sim1,rel0,rel1}
{
    // XCD-chunked swizzle: each XCD walks a contiguous slice of bin space
    const int data = ((blockIdx.x & 7) * (NWGS / 8)) + (blockIdx.x >> 3);
    const int tid = threadIdx.x;
    const int grp = tid >> 4, gl = tid & 15, cg = gl * 16;
    const int slot0 = data * 32 + grp * 2;

    unsigned sid[2];
    sid[0] = order[slot0];
    sid[1] = order[slot0 + 1];

    int bb[2], kv[2], nv[2];
    float gx[2], gy[2], wr[2];
    f16x2 nf2[2][8];
#pragma unroll
    for (int j = 0; j < 2; ++j) {
        const unsigned s = sid[j];
        nv[j] = s & 511; kv[j] = (s >> 9) & 127; bb[j] = (int)(s >> 16);
        gx[j] = coords[(size_t)s * 2 + 0];
        gy[j] = coords[(size_t)s * 2 + 1];
        wr[j] = nodew[bb[j] * N + nv[j]];
        const f16* np_ = nnf + ((size_t)(bb[j] * N + nv[j])) * C + cg;
        float4 r0 = *reinterpret_cast<const float4*>(np_);
        float4 r1 = *reinterpret_cast<const float4*>(np_ + 8);
        const f16x2* h0 = reinterpret_cast<const f16x2*>(&r0);
        const f16x2* h1 = reinterpret_cast<const f16x2*>(&r1);
#pragma unroll
        for (int c = 0; c < 4; ++c) { nf2[j][c] = h0[c]; nf2[j][c + 4] = h1[c]; }
    }

    // precompute 4 phases (ph: j=ph&1, s=ph>>1): taps, weights, rel blends
    int   pp[4][4];
    f16x2 ww[4][4];
    float srv[4];
    const f16* fb[4];
#pragma unroll
    for (int ph = 0; ph < 4; ++ph) {
        const int j = ph & 1, s = ph >> 1;
        const int W_ = s ? W16 : W8;
        const int H_ = s ? H16 : H8;
        const float* __restrict__ relm =
            (s ? rel16 : rel8) + (size_t)bb[j] * (s ? P16 : P8);
        fb[ph] = (s ? ft16 : ft8) + (size_t)bb[j] * (s ? P16 : P8) * C;

        const float ix = ((gx[j] + 1.0f) * W_ - 1.0f) * 0.5f;
        const float iy = ((gy[j] + 1.0f) * H_ - 1.0f) * 0.5f;
        const float x0f = floorf(ix), y0f = floorf(iy);
        const int x0 = (int)x0f, y0 = (int)y0f;
        const int x1 = x0 + 1, y1 = y0 + 1;
        const float fx1 = ix - x0f, fx0 = 1.0f - fx1;
        const float fy1 = iy - y0f, fy0 = 1.0f - fy1;
        const bool vx0 = (x0 >= 0) && (x0 < W_);
        const bool vx1 = (x1 >= 0) && (x1 < W_);
        const bool vy0 = (y0 >= 0) && (y0 < H_);
        const bool vy1 = (y1 >= 0) && (y1 < H_);
        float w[4];
        w[0] = (vx0 && vy0) ? fx0 * fy0 : 0.0f;
        w[1] = (vx1 && vy0) ? fx1 * fy0 : 0.0f;
        w[2] = (vx0 && vy1) ? fx0 * fy1 : 0.0f;
        w[3] = (vx1 && vy1) ? fx1 * fy1 : 0.0f;
        const int cx0 = min(max(x0, 0), W_ - 1);
        const int cx1 = min(max(x1, 0), W_ - 1);
        const int cy0 = min(max(y0, 0), H_ - 1);
        const int cy1 = min(max(y1, 0), H_ - 1);
        pp[ph][0] = cy0 * W_ + cx0; pp[ph][1] = cy0 * W_ + cx1;
        pp[ph][2] = cy1 * W_ + cx0; pp[ph][3] = cy1 * W_ + cx1;
        srv[ph] = w[0] * relm[pp[ph][0]] + w[1] * relm[pp[ph][1]]
                + w[2] * relm[pp[ph][2]] + w[3] * relm[pp[ph][3]];
#pragma unroll
        for (int t = 0; t < 4; ++t) {
            const f16 h = (f16)w[t];
            ww[ph][t] = f16x2{h, h};
        }
    }

    // depth-2 pipelined: load phase ph+1 while computing ph
    float4 ra[2][4], rb[2][4];
#pragma unroll
    for (int t = 0; t < 4; ++t) {
        const f16* tp = fb[0] + (size_t)pp[0][t] * C + cg;
        ra[0][t] = *reinterpret_cast<const float4*>(tp);
        rb[0][t] = *reinterpret_cast<const float4*>(tp + 8);
    }

    float simv[4];
#pragma unroll
    for (int ph = 0; ph < 4; ++ph) {
        const int cur = ph & 1, nxt = cur ^ 1;
        if (ph < 3) {
#pragma unroll
            for (int t = 0; t < 4; ++t) {
                const f16* tp = fb[ph + 1] + (size_t)pp[ph + 1][t] * C + cg;
                ra[nxt][t] = *reinterpret_cast<const float4*>(tp);
                rb[nxt][t] = *reinterpret_cast<const float4*>(tp + 8);
            }
        }

        f16x2 v[8];
        {
            const f16x2* a0 = reinterpret_cast<const f16x2*>(&ra[cur][0]);
            const f16x2* b0 = reinterpret_cast<const f16x2*>(&rb[cur][0]);
#pragma unroll
            for (int c = 0; c < 4; ++c) {
                v[c]     = ww[ph][0] * a0[c];
                v[c + 4] = ww[ph][0] * b0[c];
            }
        }
#pragma unroll
        for (int t = 1; t < 4; ++t) {
            const f16x2* at = reinterpret_cast<const f16x2*>(&ra[cur][t]);
            const f16x2* bt = reinterpret_cast<const f16x2*>(&rb[cur][t]);
#pragma unroll
            for (int c = 0; c < 4; ++c) {
                v[c]     += ww[ph][t] * at[c];
                v[c + 4] += ww[ph][t] * bt[c];
            }
        }

        float dot = 0.0f, n2 = 0.0f;
        const int j = ph & 1;
#pragma unroll
        for (int c = 0; c < 8; ++c) {
            dot = fdot2a(nf2[j][c], v[c], dot);
            n2  = fdot2a(v[c], v[c], n2);
        }
        dot = red16_sum(dot);
        n2  = red16_sum(n2);
        simv[ph] = dot * __frsqrt_rn(fmaxf(n2, 1e-24f));
    }

    if (gl == 0) {
#pragma unroll
        for (int j = 0; j < 2; ++j) {
            sr[(size_t)(bb[j] * K + kv[j]) * N + nv[j]] =
                make_float4(simv[j], simv[2 + j],
                            wr[j] + srv[j], wr[j] + srv[2 + j]);
        }
    }
}

// per (b,k): softmax over N*S of rel, weighted sum of sim
__global__ __launch_bounds__(256) void k_logits(
    const float4* __restrict__ sr, const float* __restrict__ lscale,
    float* __restrict__ logits)
{
    const int bk = blockIdx.x;
    const int tid = threadIdx.x;
    const int lane = tid & 63, wid = tid >> 6;
    const float4* sp = sr + (size_t)bk * N;
    __shared__ float red0[4], red1[4], red2[4];

    float4 e0 = sp[tid], e1 = sp[tid + 256];
    float m = fmaxf(fmaxf(e0.z, e0.w), fmaxf(e1.z, e1.w));
#pragma unroll
    for (int off = 32; off; off >>= 1) m = fmaxf(m, __shfl_xor(m, off));
    if (lane == 0) red0[wid] = m;
    __syncthreads();
    m = fmaxf(fmaxf(red0[0], red0[1]), fmaxf(red0[2], red0[3]));

    const float a0 = expf(e0.z - m), a1 = expf(e0.w - m);
    const float b0 = expf(e1.z - m), b1 = expf(e1.w - m);
    float se = a0 + a1 + b0 + b1;
    float ss = a0 * e0.x + a1 * e0.y + b0 * e1.x + b1 * e1.y;
#pragma unroll
    for (int off = 32; off; off >>= 1) {
        se += __shfl_xor(se, off);
        ss += __shfl_xor(ss, off);
    }
    if (lane == 0) { red1[wid] = se; red2[wid] = ss; }
    __syncthreads();
    if (tid == 0) {
        const float tse = red1[0] + red1[1] + red1[2] + red1[3];
        const float tss = red2[0] + red2[1] + red2[2] + red2[3];
        logits[bk] = (tss / tse) * expf(lscale[0]);
    }
}

// final softmax over K per b
__global__ __launch_bounds__(64) void k_out(
    const float* __restrict__ logits, float* __restrict__ out)
{
    const int b = blockIdx.x;
    const int lane = threadIdx.x;
    const float v0 = logits[b * K + lane];
    const float v1 = logits[b * K + lane + 64];
    float m = fmaxf(v0, v1);
#pragma unroll
    for (int off = 32; off; off >>= 1) m = fmaxf(m, __shfl_xor(m, off));
    const float e0 = expf(v0 - m), e1 = expf(v1 - m);
    float se = e0 + e1;
#pragma unroll
    for (int off = 32; off; off >>= 1) se += __shfl_xor(se, off);
    out[b * K + lane] = e0 / se;
    out[b * K + lane + 64] = e1 / se;
}

extern "C" void kernel_launch(void* const* d_in, const int* in_sizes, int n_in,
                              void* d_out, int out_size, void* d_ws, size_t ws_size,
                              hipStream_t stream)
{
    const float* nodew  = (const float*)d_in[0];
    const float* nodef  = (const float*)d_in[1];
    const float* rel8   = (const float*)d_in[2];
    const float* feat8  = (const float*)d_in[3];
    const float* rel16  = (const float*)d_in[4];
    const float* feat16 = (const float*)d_in[5];
    const float* coords = (const float*)d_in[6];
    const float* lscale = (const float*)d_in[7];

    char* ws = (char*)d_ws;
    size_t off = 0;
    f16* ft8  = (f16*)(ws + off); off += (size_t)B * P8 * C * 2;     // 33.5 MB
    f16* ft16 = (f16*)(ws + off); off += (size_t)B * P16 * C * 2;    //  8.4 MB
    f16* nnf  = (f16*)(ws + off); off += (size_t)B * N * C * 2;      //  1.0 MB
    float4* sr = (float4*)(ws + off); off += (size_t)NSAMP * 16;     //  8.4 MB
    float* logits = (float*)(ws + off); off += (size_t)B * K * 4;
    unsigned* order  = (unsigned*)(ws + off); off += (size_t)NSAMP * 4; // 2.1 MB
    unsigned* hist   = (unsigned*)(ws + off); off += NBINS * 4;
    unsigned* cursor = (unsigned*)(ws + off); off += NBINS * 4;
    float* out = (float*)d_out;

    hipMemsetAsync(hist, 0, NBINS * sizeof(unsigned), stream);

    hipLaunchKernelGGL(k_transpose, dim3(P8 / 64, C / 64, B), dim3(256), 0, stream,
                       feat8, ft8, P8);
    hipLaunchKernelGGL(k_transpose, dim3(P16 / 64, C / 64, B), dim3(256), 0, stream,
                       feat16, ft16, P16);
    hipLaunchKernelGGL(k_prenorm, dim3(B * N / 4), dim3(256), 0, stream,
                       nodef, nnf);
    hipLaunchKernelGGL(k_count, dim3(NSAMP / 512), dim3(256), 0, stream,
                       coords, hist);
    hipLaunchKernelGGL(k_scan, dim3(1), dim3(256), 0, stream, hist, cursor);
    hipLaunchKernelGGL(k_scatter, dim3(NSAMP / 512), dim3(256), 0, stream,
                       coords, cursor, order);
    hipLaunchKernelGGL(k_sample, dim3(NWGS), dim3(256), 0, stream,
                       nodew, nnf, rel8, rel16, coords, ft8, ft16, order, sr);
    hipLaunchKernelGGL(k_logits, dim3(B * K), dim3(256), 0, stream,
                       sr, lscale, logits);
    hipLaunchKernelGGL(k_out, dim3(B), dim3(64), 0, stream, logits, out);
}